// Round 9
// baseline (107.987 us; speedup 1.0000x reference)
//
#include <hip/hip_runtime.h>

// Composite-filter formulation:
//   out[o] = sum_{k=0..54} Cp[r][k] * x[n0 - k],
//     r = (2o+32) % 3, n0 = (2o+32-r)/3,
//     Cp[p][k] = C[p+3k], C[j] = sum_m b[m]*h[j-2m]
//
// R7:  direct-global windows, no barrier: 46us, VALUBusy 22%.
// R8 FAILED: reg double-buffer of the WINDOW, VGPR 128, occupancy halved.
// R9:  LDS tile + XOR float4-slot swizzle, 6-reg rotating window. <42.6us.
// R10 FAILED: LDS coeff table + path merge. (conflicts misattributed; see R15)
// R11: prep merge (3 dispatches -> 2). total 117 -> 108.9.
// R12 FAILED: opaque-VGPR coeff idx + occupancy cap -> scratch spills.
//   Lesson: WRITE_SIZE explosion = spill detector.
// R13: single up-front ds burst: neutral. lgkmcnt-conflation REFUTED.
// R14: wave-autonomous staging, __syncthreads deleted. 107.4.
// R15: coeffs -> lane-resident VGPR table + readlane. VGPR 64->32,
//   VALUBusy 22->37.6%, dur UNCHANGED -> coeff-fetch theory REFUTED.
//   Extra issue filled idle slots: the stall is SYNCHRONIZED across waves.
// R16: block-convoy theory. Identical-length blocks turn over in lockstep;
//   all 32 fresh waves/CU hit the staging vmcnt together -> whole-CU idle
//   per turnover. Fix: 2 tiles per wave, cross-tile software pipeline:
//   issue tile-B global loads BEFORE tile-A compute (12 held VGPRs);
//   ds_write B after A's last read (DS is in-order per wave -> no barrier,
//   single LDS buffer reused). Stalls/output halve; B-compute overlaps
//   other blocks' staging. Grid 4096 -> 2048.

#define TPB 256
#define RPT 12                    // outputs per thread per tile
#define OTILE (TPB * RPT)         // 3072 outputs per tile
#define WREG 144                  // float4 slots per wave region (144%8==0)
#define NTAPS 55
#define CPSTRIDE 56               // phase-major coeff stride (zero-padded)

#define SLOT(c) ((c) ^ (((c) >> 3) & 7))

// One dispatch, 3 independent blocks:
//   block 0: build cp[3*56] composite coefficients (same order -> bit-identical)
//   block 1: head boundary (o in [0,50))
//   block 2: tail boundary (o in [n_out, out_size))
__global__ __launch_bounds__(TPB) void prep_k(
    const float* __restrict__ x, const float* __restrict__ h,
    const float* __restrict__ b, float* __restrict__ cp,
    float* __restrict__ out, int n_in, int n_out, int out_size)
{
    __shared__ float h_s[63];
    __shared__ float b_s[51];
    __shared__ float x_s[64];
    __shared__ float u_s[50];

    const int tid = threadIdx.x;
    if (tid < 63) h_s[tid] = h[tid];
    if (tid < 51) b_s[tid] = b[tid];

    if (blockIdx.x == 0) {
        __syncthreads();
        for (int idx = tid; idx < 3 * CPSTRIDE; idx += TPB) {
            const int p = idx / CPSTRIDE;
            const int k = idx - p * CPSTRIDE;
            float acc = 0.0f;
            if (k < NTAPS) {
                const int j = p + 3 * k;
                for (int m = 0; m <= 50; ++m) {
                    const int hi = j - 2 * m;
                    if (hi >= 0 && hi <= 62) acc += b_s[m] * h_s[hi];
                }
            }
            cp[idx] = acc;
        }
    } else if (blockIdx.x == 1) {
        if (tid < 44) x_s[tid] = (tid < n_in) ? x[tid] : 0.0f;
        __syncthreads();
        if (tid < 50) {
            const int s  = 2 * tid + 32;
            const int p0 = s % 3;
            const int q  = s / 3;
            float u = 0.0f;
            #pragma unroll
            for (int i = 0; i <= 20; ++i) {
                const int xi = q - i;
                u += h_s[p0 + 3 * i] * ((xi >= 0) ? x_s[xi] : 0.0f);
            }
            u_s[tid] = u;
        }
        __syncthreads();
        if (tid < 50) {
            float acc = 0.0f;
            for (int t = 0; t <= tid; ++t) acc += b_s[tid - t] * u_s[t];
            out[tid] = acc;
        }
    } else {
        const int t0   = n_out - 50;
        const int qmin = (2 * t0 + 32) / 3;
        const int xb   = qmin - 20;
        if (tid < 64) {
            const int xi = xb + tid;
            x_s[tid] = (xi >= 0 && xi < n_in) ? x[xi] : 0.0f;
        }
        __syncthreads();
        if (tid < 50) {
            const int t  = t0 + tid;
            const int s  = 2 * t + 32;
            const int p0 = s % 3;
            const int q  = s / 3;
            const int base = q - xb;
            float u = 0.0f;
            #pragma unroll
            for (int i = 0; i <= 20; ++i)
                u += h_s[p0 + 3 * i] * x_s[base - i];
            u_s[tid] = u;
        }
        __syncthreads();
        const int n_tail = out_size - n_out;   // 96
        if (tid < n_tail) {
            float acc = 0.0f;
            for (int j = tid; j <= 49; ++j) acc += b_s[tid + 50 - j] * u_s[j];
            out[n_out + tid] = acc;
        }
    }
}

// Coefficient fetch: flat index i (compile-time constant) -> value held in
// lane (i&63) of table reg (i>>6). readlane result is wave-uniform (SGPR).
__device__ __forceinline__ float co(const int i, const int c0,
                                    const int c1, const int c2) {
    const int ln = i & 63;
    const int v = (i < 64)  ? __builtin_amdgcn_readlane(c0, ln)
                : (i < 128) ? __builtin_amdgcn_readlane(c1, ln)
                            : __builtin_amdgcn_readlane(c2, ln);
    return __int_as_float(v);
}

// Group g covers taps k=4g..4g+3 for 12 outputs d=0..11.
// delta_d = {0,1,2,2,3,4,4,5,6,6,7,8}, phase r_d = (2+2d)%3 -> q2/q1/q0 cycle.
// Flat coeff idx: q0 = 4g+j, q1 = 56+4g+j, q2 = 112+4g+j.
#define GRP12(g, A, B, C, D) {                                          \
    const float q2x = co(112 + 4*(g), cc0, cc1, cc2);                   \
    const float q2y = co(113 + 4*(g), cc0, cc1, cc2);                   \
    const float q2z = co(114 + 4*(g), cc0, cc1, cc2);                   \
    const float q2w = co(115 + 4*(g), cc0, cc1, cc2);                   \
    const float q1x = co( 56 + 4*(g), cc0, cc1, cc2);                   \
    const float q1y = co( 57 + 4*(g), cc0, cc1, cc2);                   \
    const float q1z = co( 58 + 4*(g), cc0, cc1, cc2);                   \
    const float q1w = co( 59 + 4*(g), cc0, cc1, cc2);                   \
    const float q0x = co(      4*(g), cc0, cc1, cc2);                   \
    const float q0y = co(  1 + 4*(g), cc0, cc1, cc2);                   \
    const float q0z = co(  2 + 4*(g), cc0, cc1, cc2);                   \
    const float q0w = co(  3 + 4*(g), cc0, cc1, cc2);                   \
    /* j=0 */                                                           \
    a0  += q2x * C.z;  a1  += q1x * C.w;  a2  += q0x * B.x;             \
    a3  += q2x * B.x;  a4  += q1x * B.y;  a5  += q0x * B.z;             \
    a6  += q2x * B.z;  a7  += q1x * B.w;  a8  += q0x * A.x;             \
    a9  += q2x * A.x;  a10 += q1x * A.y;  a11 += q0x * A.z;             \
    /* j=1 */                                                           \
    a0  += q2y * C.y;  a1  += q1y * C.z;  a2  += q0y * C.w;             \
    a3  += q2y * C.w;  a4  += q1y * B.x;  a5  += q0y * B.y;             \
    a6  += q2y * B.y;  a7  += q1y * B.z;  a8  += q0y * B.w;             \
    a9  += q2y * B.w;  a10 += q1y * A.x;  a11 += q0y * A.y;             \
    /* j=2 */                                                           \
    a0  += q2z * C.x;  a1  += q1z * C.y;  a2  += q0z * C.z;             \
    a3  += q2z * C.z;  a4  += q1z * C.w;  a5  += q0z * B.x;             \
    a6  += q2z * B.x;  a7  += q1z * B.y;  a8  += q0z * B.z;             \
    a9  += q2z * B.z;  a10 += q1z * B.w;  a11 += q0z * A.x;             \
    /* j=3 */                                                           \
    a0  += q2w * D.w;  a1  += q1w * C.x;  a2  += q0w * C.y;             \
    a3  += q2w * C.y;  a4  += q1w * C.z;  a5  += q0w * C.w;             \
    a6  += q2w * C.w;  a7  += q1w * B.x;  a8  += q0w * B.y;             \
    a9  += q2w * B.y;  a10 += q1w * B.z;  a11 += q0w * B.w; }

// Tail group: j=0..2 only (k = 52,53,54).
#define GRP12T(g, A, B, C) {                                            \
    const float q2x = co(112 + 4*(g), cc0, cc1, cc2);                   \
    const float q2y = co(113 + 4*(g), cc0, cc1, cc2);                   \
    const float q2z = co(114 + 4*(g), cc0, cc1, cc2);                   \
    const float q1x = co( 56 + 4*(g), cc0, cc1, cc2);                   \
    const float q1y = co( 57 + 4*(g), cc0, cc1, cc2);                   \
    const float q1z = co( 58 + 4*(g), cc0, cc1, cc2);                   \
    const float q0x = co(      4*(g), cc0, cc1, cc2);                   \
    const float q0y = co(  1 + 4*(g), cc0, cc1, cc2);                   \
    const float q0z = co(  2 + 4*(g), cc0, cc1, cc2);                   \
    a0  += q2x * C.z;  a1  += q1x * C.w;  a2  += q0x * B.x;             \
    a3  += q2x * B.x;  a4  += q1x * B.y;  a5  += q0x * B.z;             \
    a6  += q2x * B.z;  a7  += q1x * B.w;  a8  += q0x * A.x;             \
    a9  += q2x * A.x;  a10 += q1x * A.y;  a11 += q0x * A.z;             \
    a0  += q2y * C.y;  a1  += q1y * C.z;  a2  += q0y * C.w;             \
    a3  += q2y * C.w;  a4  += q1y * B.x;  a5  += q0y * B.y;             \
    a6  += q2y * B.y;  a7  += q1y * B.z;  a8  += q0y * B.w;             \
    a9  += q2y * B.w;  a10 += q1y * A.x;  a11 += q0y * A.y;             \
    a0  += q2z * C.x;  a1  += q1z * C.y;  a2  += q0z * C.z;             \
    a3  += q2z * C.z;  a4  += q1z * C.w;  a5  += q0z * B.x;             \
    a6  += q2z * B.x;  a7  += q1z * B.y;  a8  += q0z * B.z;             \
    a9  += q2z * B.z;  a10 += q1z * B.w;  a11 += q0z * A.x; }

// Guarded staging for boundary tiles (first/last block only).
#define EDGE_STAGE(NT) {                                                \
    const int fb0 = (NT) + 512 * w;                                     \
    _Pragma("unroll")                                                   \
    for (int s = 0; s < 3; ++s) {                                       \
        const int c = l + 64 * s;                                       \
        if (c > 141) break;                                             \
        const int fb = fb0 + 4 * c;                                     \
        float4 v;                                                       \
        v.x = (fb + 0 >= 0 && fb + 0 < n_in) ? x[fb + 0] : 0.0f;        \
        v.y = (fb + 1 >= 0 && fb + 1 < n_in) ? x[fb + 1] : 0.0f;        \
        v.z = (fb + 2 >= 0 && fb + 2 < n_in) ? x[fb + 2] : 0.0f;        \
        v.w = (fb + 3 >= 0 && fb + 3 < n_in) ? x[fb + 3] : 0.0f;        \
        xs4[wreg + SLOT(c)] = v;                                        \
    } }

#define XS(j) xs4[wreg + SLOT(2 * l + (j))]

// Full per-tile compute: 6-reg rotating window + 12-output store.
#define TILE_COMPUTE(OB) {                                              \
    float a0 = 0.f, a1 = 0.f, a2 = 0.f, a3  = 0.f, a4  = 0.f, a5 = 0.f;\
    float a6 = 0.f, a7 = 0.f, a8 = 0.f, a9  = 0.f, a10 = 0.f, a11 = 0.f;\
    {                                                                   \
        float4 r0 = XS(15), r1 = XS(14), r2 = XS(13),                   \
               r3 = XS(12), r4 = XS(11), r5 = XS(10);                   \
        GRP12( 0, r0, r1, r2, r3);  r0 = XS(9);                         \
        GRP12( 1, r1, r2, r3, r4);  r1 = XS(8);                         \
        GRP12( 2, r2, r3, r4, r5);  r2 = XS(7);                         \
        GRP12( 3, r3, r4, r5, r0);  r3 = XS(6);                         \
        GRP12( 4, r4, r5, r0, r1);  r4 = XS(5);                         \
        GRP12( 5, r5, r0, r1, r2);  r5 = XS(4);                         \
        GRP12( 6, r0, r1, r2, r3);  r0 = XS(3);                         \
        GRP12( 7, r1, r2, r3, r4);  r1 = XS(2);                         \
        GRP12( 8, r2, r3, r4, r5);  r2 = XS(1);                         \
        GRP12( 9, r3, r4, r5, r0);  r3 = XS(0);                         \
        GRP12(10, r4, r5, r0, r1);                                      \
        GRP12(11, r5, r0, r1, r2);                                      \
        GRP12(12, r0, r1, r2, r3);                                      \
        GRP12T(13, r1, r2, r3);                                         \
    }                                                                   \
    const int ob_ = (OB);                                               \
    if (ob_ >= 50 && ob_ + 11 < n_out) {                                \
        float4* o4 = (float4*)(out + ob_);   /* 16B aligned */          \
        o4[0] = make_float4(a0, a1, a2,  a3);                           \
        o4[1] = make_float4(a4, a5, a6,  a7);                           \
        o4[2] = make_float4(a8, a9, a10, a11);                          \
    } else {                                                            \
        const float accs[RPT] = {a0,a1,a2,a3,a4,a5,a6,a7,a8,a9,a10,a11};\
        _Pragma("unroll")                                               \
        for (int d = 0; d < RPT; ++d) {                                 \
            const int o = ob_ + d;                                      \
            if (o >= 50 && o < n_out) out[o] = accs[d];                 \
        }                                                               \
    } }

__global__ __launch_bounds__(TPB) void fused_fast(
    const float* __restrict__ x, const float* __restrict__ cp,
    float* __restrict__ out, int n_in, int n_out)
{
    __shared__ float4 xs4[4 * WREG];   // single buffer, per-wave regions

    const int tid = threadIdx.x;
    const int w   = tid >> 6;                    // wave id 0..3
    const int l   = tid & 63;                    // lane
    const int bt  = blockIdx.x;
    const int o0  = bt * (2 * OTILE);            // 6144 outputs per block
    const int ntA = 4096 * bt - 44;              // tile A x-base (mult of 4)
    const int ntB = ntA + 2048;                  // tile B x-base
    const int wreg = w * WREG;

    // lane-resident coefficient table: 3 VGPRs cover all 168 floats
    const int cc0 = __float_as_int(cp[l]);
    const int cc1 = __float_as_int(cp[l + 64]);
    const int cc2 = __float_as_int(cp[(l < 40) ? (128 + l) : 128]);

    const bool intA = (ntA >= 0) && (ntA + 2104 <= n_in);
    const bool intB = (ntB >= 0) && (ntB + 2104 <= n_in);

    // ---- issue BOTH tiles' global loads up front (cross-tile pipeline) ----
    float4 ga0, ga1, ga2, gb0, gb1, gb2;
    if (intA) {
        const float4* gw = (const float4*)(x + ntA) + 128 * w;
        ga0 = gw[l];
        ga1 = gw[l + 64];
        if (l < 14) ga2 = gw[l + 128];
    }
    if (intB) {
        const float4* gw = (const float4*)(x + ntB) + 128 * w;
        gb0 = gw[l];
        gb1 = gw[l + 64];
        if (l < 14) gb2 = gw[l + 128];
    }
    __builtin_amdgcn_sched_barrier(0);   // pin prefetch issue point

    // ---- stage + compute tile A ----
    if (intA) {
        xs4[wreg + SLOT(l)]      = ga0;          // vmcnt waits only A-loads
        xs4[wreg + SLOT(l + 64)] = ga1;          // (B-loads stay in flight)
        if (l < 14) xs4[wreg + SLOT(l + 128)] = ga2;
    } else {
        EDGE_STAGE(ntA);
    }
    TILE_COMPUTE(o0 + RPT * tid);

    // ---- stage + compute tile B ----
    // DS is in-order per wave: these writes execute after tile A's last
    // ds_read; gb* landed long ago under tile A's FMA stream. No barrier.
    if (intB) {
        xs4[wreg + SLOT(l)]      = gb0;
        xs4[wreg + SLOT(l + 64)] = gb1;
        if (l < 14) xs4[wreg + SLOT(l + 128)] = gb2;
    } else {
        EDGE_STAGE(ntB);
    }
    TILE_COMPUTE(o0 + OTILE + RPT * tid);
}

extern "C" void kernel_launch(void* const* d_in, const int* in_sizes, int n_in_arrs,
                              void* d_out, int out_size, void* d_ws, size_t ws_size,
                              hipStream_t stream) {
    const float* x = (const float*)d_in[0];
    const float* h = (const float*)d_in[1];
    const float* b = (const float*)d_in[2];
    float* out = (float*)d_out;
    float* cp  = (float*)d_ws;                        // 3*56*4 = 672 bytes

    const int n_in  = in_sizes[0];                    // 8388608
    const int n_out = (int)((long long)n_in * 3 / 2); // 12582912

    prep_k<<<3, TPB, 0, stream>>>(x, h, b, cp, out, n_in, n_out, out_size);

    const int nblocks = (n_out + 2 * OTILE - 1) / (2 * OTILE);  // 2048
    fused_fast<<<nblocks, TPB, 0, stream>>>(x, cp, out, n_in, n_out);
}